// Round 5
// baseline (645.807 us; speedup 1.0000x reference)
//
#include <hip/hip_runtime.h>

#define S_LEN 2048
#define NH 16
#define DIM 128
#define KSZ 32
#define STRD 16
#define SSZ 64
#define NSELB 32
#define NCMP 127
#define TOPN 16
#define WINSZ 512
#define NEGF (-1e30f)
#define NEGTH (-1e29f)
#define SCALE 0.088388347648318447f

typedef __attribute__((ext_vector_type(8))) short bf16x8;
typedef __attribute__((ext_vector_type(4))) float f32x4;

__device__ __forceinline__ unsigned short f2bf(float f) {
  unsigned u = __builtin_bit_cast(unsigned, f);
  return (unsigned short)((u + 0x7FFFu + ((u >> 16) & 1u)) >> 16);
}
__device__ __forceinline__ float bf2f(unsigned short b) {
  return __builtin_bit_cast(float, (unsigned)b << 16);
}
__device__ __forceinline__ bf16x8 pack8(const float* f) {
  bf16x8 r;
#pragma unroll
  for (int i = 0; i < 8; ++i) r[i] = (short)f2bf(f[i]);
  return r;
}

// sub-padded score layout: 4 groups of 32 cols at stride 33 (bank-spread)
#define SCIDX(r, c) ((r) * 132 + (((c) >> 5) * 33) + ((c) & 31))

// ---------- kernel 1: build vtg[h][d][t] and kb[h][t][d], both bf16 ----------
__global__ __launch_bounds__(256) void nsa_build(
    const float* __restrict__ v, const float* __restrict__ k,
    unsigned short* __restrict__ vtg, unsigned short* __restrict__ kb) {
  const int c = blockIdx.x * 256 + threadIdx.x;   // 524288 chunks of 8
  {
    const int h = c >> 15, d = (c >> 8) & 127, tc = c & 255;
    float f[8];
#pragma unroll
    for (int i = 0; i < 8; ++i) f[i] = v[((tc * 8 + i) * NH + h) * DIM + d];
    *(bf16x8*)(vtg + ((h * DIM + d) * S_LEN + tc * 8)) = pack8(f);
  }
  {
    const int h = c >> 15, t = (c >> 4) & 2047, dc = c & 15;
    const float* src = k + ((t * NH + h) * DIM + dc * 8);
    float f[8];
#pragma unroll
    for (int i = 0; i < 8; ++i) f[i] = src[i];
    *(bf16x8*)(kb + ((h * S_LEN + t) * DIM + dc * 8)) = pack8(f);
  }
}

// ---------- kernel 2: compress; cmpk hi/lo bf16, cmpv transposed bf16 ----------
__global__ __launch_bounds__(128) void nsa_compress(
    const float* __restrict__ k, const float* __restrict__ v,
    unsigned short* __restrict__ cmpkh, unsigned short* __restrict__ cmpkl,
    unsigned short* __restrict__ cmpvt) {
  const int c = blockIdx.x & 127;
  const int h = blockIdx.x >> 7;
  const int d = threadIdx.x;
  float sk = 0.f, sv = 0.f;
  if (c < NCMP) {
    const int base = ((c * STRD) * NH + h) * DIM + d;
#pragma unroll
    for (int i = 0; i < KSZ; ++i) {
      sk += k[base + i * NH * DIM];
      sv += v[base + i * NH * DIM];
    }
    sk *= (1.0f / KSZ); sv *= (1.0f / KSZ);
  }
  const unsigned short hi = f2bf(sk);
  const unsigned short lo = f2bf(sk - bf2f(hi));
  cmpkh[(h * 128 + c) * 128 + d] = (c < NCMP) ? hi : 0;
  cmpkl[(h * 128 + c) * 128 + d] = (c < NCMP) ? lo : 0;
  cmpvt[(h * 128 + d) * 128 + c] = (c < NCMP) ? f2bf(sv) : 0;
}

// ---------- kernel 3: main fused NSA ----------
// block = (h, 16 queries), 128 threads = 2 waves.
// wave 0 (S): cmp QK(hi/lo) + softmax + selection + selected branch + epilogue
// wave 1 (W): gates + cmp PV + window branch; hands winOut via LDS
__global__ __launch_bounds__(128, 4) void nsa_main(
    const float* __restrict__ q, const float* __restrict__ wg,
    const float* __restrict__ bg, const unsigned short* __restrict__ kb,
    const unsigned short* __restrict__ vtg,
    const unsigned short* __restrict__ cmpkh, const unsigned short* __restrict__ cmpkl,
    const unsigned short* __restrict__ cmpvt, float* __restrict__ out) {
  __shared__ float scw[16 * 132];                 // scores -> probs -> winOut
  __shared__ __align__(16) char pa[2 * 1024];     // per-wave P bf16 [16 rows][64B]
  __shared__ float ssel[16 * 33];
  __shared__ float gatesLds[48];
  __shared__ unsigned maskLds[16];

  // XCD swizzle: heads (2x, 2x+1) -> XCD x (L2 working set ~4.4 MB/XCD)
  const int b = blockIdx.x;
  const int h = ((b & 7) << 1) | ((b >> 3) & 1);
  const int t0 = (b >> 4) << 4;

  const int tid = threadIdx.x;
  const int lane = tid & 63;
  const int w = tid >> 6;
  const int l15 = lane & 15;
  const int l4 = lane >> 4;

  const int nvmax = t0 >> 4;                 // max valid cmp blocks in this tile
  const int nct = (nvmax + 31) >> 5;         // cmp ct-tiles actually needed

  // ---- Q fragments (hi for both waves; lo used by S only) ----
  bf16x8 qfh[4], qfl[4];
  {
    const float* qp = q + ((t0 + l15) * NH + h) * DIM + l4 * 8;
#pragma unroll
    for (int ks = 0; ks < 4; ++ks) {
      bf16x8 hh, ll;
#pragma unroll
      for (int i = 0; i < 8; ++i) {
        const float x = qp[ks * 32 + i];
        const unsigned short hb = f2bf(x);
        hh[i] = (short)hb;
        ll[i] = (short)f2bf(x - bf2f(hb));
      }
      qfh[ks] = hh; qfl[ks] = ll;
    }
  }

  unsigned maskq[4] = {0, 0, 0, 0};
  unsigned unionW = 0;

  if (w == 0) {
    // ================= S: compressed QK (hi/lo) =================
    if (lane < 16) maskLds[lane] = 0u;
    for (int ct = 0; ct < nct; ++ct) {
      const unsigned short* bk = cmpkh + (h * 128 + ct * 32) * 128 + l4 * 8;
      const unsigned short* bkl = cmpkl + (h * 128 + ct * 32) * 128 + l4 * 8;
      f32x4 s0 = {0, 0, 0, 0}, s1 = {0, 0, 0, 0};
#pragma unroll
      for (int ks = 0; ks < 4; ++ks) {
        bf16x8 bh0 = *(const bf16x8*)(bk + l15 * 128 + ks * 32);
        bf16x8 bh1 = *(const bf16x8*)(bk + (16 + l15) * 128 + ks * 32);
        bf16x8 bl0 = *(const bf16x8*)(bkl + l15 * 128 + ks * 32);
        bf16x8 bl1 = *(const bf16x8*)(bkl + (16 + l15) * 128 + ks * 32);
        s0 = __builtin_amdgcn_mfma_f32_16x16x32_bf16(qfh[ks], bh0, s0, 0, 0, 0);
        s0 = __builtin_amdgcn_mfma_f32_16x16x32_bf16(qfl[ks], bh0, s0, 0, 0, 0);
        s0 = __builtin_amdgcn_mfma_f32_16x16x32_bf16(qfh[ks], bl0, s0, 0, 0, 0);
        s1 = __builtin_amdgcn_mfma_f32_16x16x32_bf16(qfh[ks], bh1, s1, 0, 0, 0);
        s1 = __builtin_amdgcn_mfma_f32_16x16x32_bf16(qfl[ks], bh1, s1, 0, 0, 0);
        s1 = __builtin_amdgcn_mfma_f32_16x16x32_bf16(qfh[ks], bl1, s1, 0, 0, 0);
      }
#pragma unroll
      for (int j = 0; j < 4; ++j) {
        const int qr = l4 * 4 + j;
        scw[SCIDX(qr, ct * 32 + l15)] = s0[j] * SCALE;
        scw[SCIDX(qr, ct * 32 + 16 + l15)] = s1[j] * SCALE;
      }
    }
    // ---- softmax over 127 cmp scores (in-wave; 4 lanes per query) ----
    {
      const int qq = lane >> 2, qg = lane & 3;
      const int tq = t0 + qq;
      const int nv = (tq >= KSZ - 1) ? ((tq - (KSZ - 1)) / STRD + 1) : 0;
      float x[32];
#pragma unroll
      for (int i = 0; i < 32; ++i) x[i] = scw[SCIDX(qq, qg * 32 + i)];
      float m = NEGF;
#pragma unroll
      for (int i = 0; i < 32; ++i)
        if (qg * 32 + i < nv) m = fmaxf(m, x[i]);
      m = fmaxf(m, __shfl_xor(m, 1));
      m = fmaxf(m, __shfl_xor(m, 2));
      float s = 0.f;
#pragma unroll
      for (int i = 0; i < 32; ++i) {
        x[i] = (qg * 32 + i < nv) ? __expf(x[i] - m) : 0.f;
        s += x[i];
      }
      s += __shfl_xor(s, 1);
      s += __shfl_xor(s, 2);
      const float inv = (nv > 0) ? (1.0f / s) : 0.f;
#pragma unroll
      for (int i = 0; i < 32; ++i) scw[SCIDX(qq, qg * 32 + i)] = x[i] * inv;
    }
    // ---- selection scores + top-16 (exact tie semantics) ----
    {
      const int qq = lane >> 2, jg = lane & 3;
      const int tq = t0 + qq;
      float vj[8];
#pragma unroll
      for (int i = 0; i < 8; ++i) {
        const int j = jg * 8 + i;
        const int lo = (4 * j - 1 > 0) ? 4 * j - 1 : 0;
        const int hi = (4 * j + 3 < NCMP - 1) ? 4 * j + 3 : NCMP - 1;
        float ps = 0.f;
        for (int c = lo; c <= hi; ++c) ps += scw[SCIDX(qq, c)];
        float val = (j * SSZ <= tq) ? ps : -1.0f;
        if (j == (tq >> 6)) val += 1e6f;
        vj[i] = val;
        ssel[qq * 33 + j] = val;
      }
      float sv[32];
#pragma unroll
      for (int jp = 0; jp < 32; ++jp) sv[jp] = ssel[qq * 33 + jp];
#pragma unroll
      for (int i = 0; i < 8; ++i) {
        const int j = jg * 8 + i;
        const float my = vj[i];
        int rank = 0;
#pragma unroll
        for (int jp = 0; jp < 32; ++jp)
          rank += (sv[jp] > my) || (sv[jp] == my && jp < j);
        if (rank < TOPN && (j * SSZ <= tq)) atomicOr(&maskLds[qq], 1u << j);
      }
    }
#pragma unroll
    for (int j = 0; j < 4; ++j) maskq[j] = maskLds[l4 * 4 + j];
    unionW = maskq[0] | maskq[1] | maskq[2] | maskq[3];
    unionW |= __shfl_xor(unionW, 16);
    unionW |= __shfl_xor(unionW, 32);
  } else {
    // ================= W: gates (fp32 exact) =================
    if (lane < 48) {
      const int qloc = lane / 3, g = lane % 3;
      const float* qr_ = q + ((t0 + qloc) * NH + h) * DIM;
      float acc = bg[g];
#pragma unroll
      for (int d4 = 0; d4 < DIM; d4 += 4) {
        const float4 qv = *(const float4*)(qr_ + d4);
        acc += qv.x * wg[(d4 + 0) * 3 + g] + qv.y * wg[(d4 + 1) * 3 + g] +
               qv.z * wg[(d4 + 2) * 3 + g] + qv.w * wg[(d4 + 3) * 3 + g];
      }
      gatesLds[qloc * 3 + g] = 1.0f / (1.0f + __expf(-acc));
    }
  }

  __syncthreads();   // #1: probs + gates visible to W

  f32x4 accO[8];
#pragma unroll
  for (int n = 0; n < 8; ++n) accO[n] = (f32x4){0, 0, 0, 0};
  float mX[4], lX[4];
#pragma unroll
  for (int j = 0; j < 4; ++j) { mX[j] = NEGF; lX[j] = 0.f; }

  char* paw = pa + w * 1024;
  const int ktmax = (t0 + 15) >> 5;

  if (w == 0) {
    // ================= S: selected branch =================
    for (int kt = 0; kt <= ktmax; ++kt) {
      if (!((unionW >> (kt >> 1)) & 1u)) continue;
      const int kt0 = kt << 5;
      const unsigned short* kbase = kb + (h * S_LEN + kt0) * DIM + l4 * 8;
      f32x4 s0 = {0, 0, 0, 0}, s1 = {0, 0, 0, 0};
#pragma unroll
      for (int ks = 0; ks < 4; ++ks) {
        bf16x8 b0 = *(const bf16x8*)(kbase + l15 * DIM + ks * 32);
        bf16x8 b1 = *(const bf16x8*)(kbase + (16 + l15) * DIM + ks * 32);
        s0 = __builtin_amdgcn_mfma_f32_16x16x32_bf16(qfh[ks], b0, s0, 0, 0, 0);
        s1 = __builtin_amdgcn_mfma_f32_16x16x32_bf16(qfh[ks], b1, s1, 0, 0, 0);
      }
      bf16x8 bv[8];
      const unsigned short* vbase = vtg + (h * DIM) * S_LEN + kt0 + l4 * 8;
#pragma unroll
      for (int n = 0; n < 8; ++n)
        bv[n] = *(const bf16x8*)(vbase + (n * 16 + l15) * S_LEN);
#pragma unroll
      for (int j = 0; j < 4; ++j) {
        const int qr = l4 * 4 + j;
        const int tq = t0 + qr;
        const bool mb = (maskq[j] >> (kt >> 1)) & 1u;
        const float v0 = (mb && kt0 + l15 <= tq) ? s0[j] * SCALE : NEGF;
        const float v1 = (mb && kt0 + 16 + l15 <= tq) ? s1[j] * SCALE : NEGF;
        float rm = fmaxf(v0, v1);
        rm = fmaxf(rm, __shfl_xor(rm, 1));
        rm = fmaxf(rm, __shfl_xor(rm, 2));
        rm = fmaxf(rm, __shfl_xor(rm, 4));
        rm = fmaxf(rm, __shfl_xor(rm, 8));
        if (rm > mX[j]) {
          const float sf = __expf(mX[j] - rm);
          lX[j] *= sf;
#pragma unroll
          for (int n = 0; n < 8; ++n) accO[n][j] *= sf;
          mX[j] = rm;
        }
        const float p0 = (v0 > NEGTH) ? __expf(v0 - mX[j]) : 0.f;
        const float p1 = (v1 > NEGTH) ? __expf(v1 - mX[j]) : 0.f;
        float rs = p0 + p1;
        rs += __shfl_xor(rs, 1);
        rs += __shfl_xor(rs, 2);
        rs += __shfl_xor(rs, 4);
        rs += __shfl_xor(rs, 8);
        lX[j] += rs;
        *(unsigned short*)(paw + qr * 64 + ((l15 * 2) ^ ((qr & 3) << 4))) = f2bf(p0);
        *(unsigned short*)(paw + qr * 64 + (((16 + l15) * 2) ^ ((qr & 3) << 4))) = f2bf(p1);
      }
      bf16x8 ap = *(const bf16x8*)(paw + l15 * 64 + ((l4 * 16) ^ ((l15 & 3) << 4)));
#pragma unroll
      for (int n = 0; n < 8; ++n)
        accO[n] = __builtin_amdgcn_mfma_f32_16x16x32_bf16(ap, bv[n], accO[n], 0, 0, 0);
    }
  } else {
    // ================= W: cmp PV =================
    f32x4 accC[8];
#pragma unroll
    for (int n = 0; n < 8; ++n) accC[n] = (f32x4){0, 0, 0, 0};
    for (int ct = 0; ct < nct; ++ct) {
      float f[8];
#pragma unroll
      for (int i = 0; i < 8; ++i) f[i] = scw[SCIDX(l15, ct * 32 + l4 * 8 + i)];
      bf16x8 ap = pack8(f);
      const unsigned short* cvb = cmpvt + (h * 128) * 128 + ct * 32 + l4 * 8;
#pragma unroll
      for (int n = 0; n < 8; ++n) {
        bf16x8 bvv = *(const bf16x8*)(cvb + (n * 16 + l15) * 128);
        accC[n] = __builtin_amdgcn_mfma_f32_16x16x32_bf16(ap, bvv, accC[n], 0, 0, 0);
      }
    }
    // winOut init = g0 * Ocmp (all prob reads above are done; same-wave ordered)
#pragma unroll
    for (int j = 0; j < 4; ++j) {
      const int qr = l4 * 4 + j;
      const float g0 = gatesLds[qr * 3 + 0];
#pragma unroll
      for (int n = 0; n < 8; ++n) scw[SCIDX(qr, n * 16 + l15)] = g0 * accC[n][j];
    }
    // ================= W: window branch =================
    const int ktlo = (t0 >= WINSZ) ? ((t0 - WINSZ) >> 5) : 0;
    for (int kt = ktlo; kt <= ktmax; ++kt) {
      const int kt0 = kt << 5;
      const unsigned short* kbase = kb + (h * S_LEN + kt0) * DIM + l4 * 8;
      f32x4 s0 = {0, 0, 0, 0}, s1 = {0, 0, 0, 0};
#pragma unroll
      for (int ks = 0; ks < 4; ++ks) {
        bf16x8 b0 = *(const bf16x8*)(kbase + l15 * DIM + ks * 32);
        bf16x8 b1 = *(const bf16x8*)(kbase + (16 + l15) * DIM + ks * 32);
        s0 = __builtin_amdgcn_mfma_f32_16x16x32_bf16(qfh[ks], b0, s0, 0, 0, 0);
        s1 = __builtin_amdgcn_mfma_f32_16x16x32_bf16(qfh[ks], b1, s1, 0, 0, 0);
      }
      bf16x8 bv[8];
      const unsigned short* vbase = vtg + (h * DIM) * S_LEN + kt0 + l4 * 8;
#pragma unroll
      for (int n = 0; n < 8; ++n)
        bv[n] = *(const bf16x8*)(vbase + (n * 16 + l15) * S_LEN);
#pragma unroll
      for (int j = 0; j < 4; ++j) {
        const int qr = l4 * 4 + j;
        const int tq = t0 + qr;
        const int c0 = kt0 + l15, c1 = kt0 + 16 + l15;
        const float v0 = (c0 <= tq && c0 >= tq - WINSZ) ? s0[j] * SCALE : NEGF;
        const float v1 = (c1 <= tq && c1 >= tq - WINSZ) ? s1[j] * SCALE : NEGF;
        float rm = fmaxf(v0, v1);
        rm = fmaxf(rm, __shfl_xor(rm, 1));
        rm = fmaxf(rm, __shfl_xor(rm, 2));
        rm = fmaxf(rm, __shfl_xor(rm, 4));
        rm = fmaxf(rm, __shfl_xor(rm, 8));
        if (rm > mX[j]) {
          const float sf = __expf(mX[j] - rm);
          lX[j] *= sf;
#pragma unroll
          for (int n = 0; n < 8; ++n) accO[n][j] *= sf;
          mX[j] = rm;
        }
        const float p0 = (v0 > NEGTH) ? __expf(v0 - mX[j]) : 0.f;
        const float p1 = (v1 > NEGTH) ? __expf(v1 - mX[j]) : 0.f;
        float rs = p0 + p1;
        rs += __shfl_xor(rs, 1);
        rs += __shfl_xor(rs, 2);
        rs += __shfl_xor(rs, 4);
        rs += __shfl_xor(rs, 8);
        lX[j] += rs;
        *(unsigned short*)(paw + qr * 64 + ((l15 * 2) ^ ((qr & 3) << 4))) = f2bf(p0);
        *(unsigned short*)(paw + qr * 64 + (((16 + l15) * 2) ^ ((qr & 3) << 4))) = f2bf(p1);
      }
      bf16x8 ap = *(const bf16x8*)(paw + l15 * 64 + ((l4 * 16) ^ ((l15 & 3) << 4)));
#pragma unroll
      for (int n = 0; n < 8; ++n)
        accO[n] = __builtin_amdgcn_mfma_f32_16x16x32_bf16(ap, bv[n], accO[n], 0, 0, 0);
    }
    // fold window into winOut
#pragma unroll
    for (int j = 0; j < 4; ++j) {
      const int qr = l4 * 4 + j;
      const float g2 = gatesLds[qr * 3 + 2];
      const float rl = 1.0f / lX[j];
#pragma unroll
      for (int n = 0; n < 8; ++n)
        scw[SCIDX(qr, n * 16 + l15)] += g2 * accO[n][j] * rl;
    }
  }

  __syncthreads();   // #2: winOut ready

  if (w == 0) {
#pragma unroll
    for (int j = 0; j < 4; ++j) {
      const int qr = l4 * 4 + j;
      const int tq = t0 + qr;
      const float g1 = gatesLds[qr * 3 + 1];
      const float rl = 1.0f / lX[j];
#pragma unroll
      for (int n = 0; n < 8; ++n)
        out[(tq * NH + h) * DIM + n * 16 + l15] =
            scw[SCIDX(qr, n * 16 + l15)] + g1 * accO[n][j] * rl;
    }
  }
}

extern "C" void kernel_launch(void* const* d_in, const int* in_sizes, int n_in,
                              void* d_out, int out_size, void* d_ws, size_t ws_size,
                              hipStream_t stream) {
  const float* q  = (const float*)d_in[0];
  const float* k  = (const float*)d_in[1];
  const float* v  = (const float*)d_in[2];
  const float* wg = (const float*)d_in[3];
  const float* bg = (const float*)d_in[4];
  float* out = (float*)d_out;

  unsigned short* vtg   = (unsigned short*)d_ws;            // 8 MB
  unsigned short* kb    = vtg + NH * DIM * S_LEN;           // 8 MB
  unsigned short* cmpkh = kb + NH * S_LEN * DIM;            // 512 KB
  unsigned short* cmpkl = cmpkh + NH * 128 * 128;           // 512 KB
  unsigned short* cmpvt = cmpkl + NH * 128 * 128;           // 512 KB

  nsa_build<<<2048, 256, 0, stream>>>(v, k, vtg, kb);
  nsa_compress<<<NH * 128, 128, 0, stream>>>(k, v, cmpkh, cmpkl, cmpvt);
  nsa_main<<<2048, 128, 0, stream>>>(q, wg, bg, kb, vtg, cmpkh, cmpkl, cmpvt, out);
}

// Round 6
// 313.933 us; speedup vs baseline: 2.0571x; 2.0571x over previous
//
#include <hip/hip_runtime.h>

#define S_LEN 2048
#define NH 16
#define DIM 128
#define KSZ 32
#define STRD 16
#define SSZ 64
#define NSELB 32
#define NCMP 127
#define TOPN 16
#define WINSZ 512
#define NEGF (-1e30f)
#define NEGTH (-1e29f)
#define SCALE 0.088388347648318447f

typedef __attribute__((ext_vector_type(8))) short bf16x8;
typedef __attribute__((ext_vector_type(4))) float f32x4;

__device__ __forceinline__ unsigned short f2bf(float f) {
  unsigned u = __builtin_bit_cast(unsigned, f);
  return (unsigned short)((u + 0x7FFFu + ((u >> 16) & 1u)) >> 16);
}
__device__ __forceinline__ float bf2f(unsigned short b) {
  return __builtin_bit_cast(float, (unsigned)b << 16);
}
__device__ __forceinline__ bf16x8 pack8(const float* f) {
  bf16x8 r;
#pragma unroll
  for (int i = 0; i < 8; ++i) r[i] = (short)f2bf(f[i]);
  return r;
}

// sub-padded score layout: 4 groups of 32 cols at stride 33 (bank-spread)
#define SCIDX(r, c) ((r) * 132 + (((c) >> 5) * 33) + ((c) & 31))

// ---------- kernel 1: build vtg[h][d][t] and kb[h][t][d], both bf16 ----------
__global__ __launch_bounds__(256) void nsa_build(
    const float* __restrict__ v, const float* __restrict__ k,
    unsigned short* __restrict__ vtg, unsigned short* __restrict__ kb) {
  const int c = blockIdx.x * 256 + threadIdx.x;   // 524288 chunks of 8
  {
    const int h = c >> 15, d = (c >> 8) & 127, tc = c & 255;
    float f[8];
#pragma unroll
    for (int i = 0; i < 8; ++i) f[i] = v[((tc * 8 + i) * NH + h) * DIM + d];
    *(bf16x8*)(vtg + ((h * DIM + d) * S_LEN + tc * 8)) = pack8(f);
  }
  {
    const int h = c >> 15, t = (c >> 4) & 2047, dc = c & 15;
    const float* src = k + ((t * NH + h) * DIM + dc * 8);
    float f[8];
#pragma unroll
    for (int i = 0; i < 8; ++i) f[i] = src[i];
    *(bf16x8*)(kb + ((h * S_LEN + t) * DIM + dc * 8)) = pack8(f);
  }
}

// ---------- kernel 2: compress; cmpk hi/lo bf16, cmpv transposed bf16 ----------
__global__ __launch_bounds__(128) void nsa_compress(
    const float* __restrict__ k, const float* __restrict__ v,
    unsigned short* __restrict__ cmpkh, unsigned short* __restrict__ cmpkl,
    unsigned short* __restrict__ cmpvt) {
  const int c = blockIdx.x & 127;
  const int h = blockIdx.x >> 7;
  const int d = threadIdx.x;
  float sk = 0.f, sv = 0.f;
  if (c < NCMP) {
    const int base = ((c * STRD) * NH + h) * DIM + d;
#pragma unroll
    for (int i = 0; i < KSZ; ++i) {
      sk += k[base + i * NH * DIM];
      sv += v[base + i * NH * DIM];
    }
    sk *= (1.0f / KSZ); sv *= (1.0f / KSZ);
  }
  const unsigned short hi = f2bf(sk);
  const unsigned short lo = f2bf(sk - bf2f(hi));
  cmpkh[(h * 128 + c) * 128 + d] = (c < NCMP) ? hi : 0;
  cmpkl[(h * 128 + c) * 128 + d] = (c < NCMP) ? lo : 0;
  cmpvt[(h * 128 + d) * 128 + c] = (c < NCMP) ? f2bf(sv) : 0;
}

// ---------- kernel 3: main fused NSA ----------
// block = (h, 16 queries), 128 threads = 2 waves, 2 barriers total.
// wave 0 (S): cmp QK(hi/lo) + softmax + selection + selected branch + epilogue
// wave 1 (W): gates + cmp PV + window branch; hands winOut via LDS
__global__ __launch_bounds__(128, 2) void nsa_main(
    const float* __restrict__ q, const float* __restrict__ wg,
    const float* __restrict__ bg, const unsigned short* __restrict__ kb,
    const unsigned short* __restrict__ vtg,
    const unsigned short* __restrict__ cmpkh, const unsigned short* __restrict__ cmpkl,
    const unsigned short* __restrict__ cmpvt, float* __restrict__ out) {
  __shared__ float scw[16 * 132];                 // scores -> probs -> winOut
  __shared__ __align__(16) char pa[2 * 1024];     // per-wave P bf16 [16 rows][64B]
  __shared__ float ssel[16 * 33];
  __shared__ float gatesLds[48];
  __shared__ unsigned maskLds[16];

  // XCD swizzle: heads (2x, 2x+1) -> XCD x (L2 hot set ~2.4 MB/XCD)
  const int b = blockIdx.x;
  const int h = ((b & 7) << 1) | ((b >> 3) & 1);
  const int t0 = (b >> 4) << 4;

  const int tid = threadIdx.x;
  const int lane = tid & 63;
  const int w = tid >> 6;
  const int l15 = lane & 15;
  const int l4 = lane >> 4;

  const int nvmax = t0 >> 4;                 // max valid cmp blocks in this tile
  const int nct = (nvmax + 31) >> 5;         // cmp ct-tiles actually needed

  // ---- Q fragments (hi for both waves; lo used by S only) ----
  bf16x8 qfh[4], qfl[4];
  {
    const float* qp = q + ((t0 + l15) * NH + h) * DIM + l4 * 8;
#pragma unroll
    for (int ks = 0; ks < 4; ++ks) {
      bf16x8 hh, ll;
#pragma unroll
      for (int i = 0; i < 8; ++i) {
        const float x = qp[ks * 32 + i];
        const unsigned short hb = f2bf(x);
        hh[i] = (short)hb;
        ll[i] = (short)f2bf(x - bf2f(hb));
      }
      qfh[ks] = hh; qfl[ks] = ll;
    }
  }

  unsigned maskq[4] = {0, 0, 0, 0};
  unsigned unionW = 0;

  if (w == 0) {
    // ================= S: compressed QK (hi/lo) =================
    if (lane < 16) maskLds[lane] = 0u;
    for (int ct = 0; ct < nct; ++ct) {
      const unsigned short* bk = cmpkh + (h * 128 + ct * 32) * 128 + l4 * 8;
      const unsigned short* bkl = cmpkl + (h * 128 + ct * 32) * 128 + l4 * 8;
      f32x4 s0 = {0, 0, 0, 0}, s1 = {0, 0, 0, 0};
#pragma unroll
      for (int ks = 0; ks < 4; ++ks) {
        bf16x8 bh0 = *(const bf16x8*)(bk + l15 * 128 + ks * 32);
        bf16x8 bh1 = *(const bf16x8*)(bk + (16 + l15) * 128 + ks * 32);
        bf16x8 bl0 = *(const bf16x8*)(bkl + l15 * 128 + ks * 32);
        bf16x8 bl1 = *(const bf16x8*)(bkl + (16 + l15) * 128 + ks * 32);
        s0 = __builtin_amdgcn_mfma_f32_16x16x32_bf16(qfh[ks], bh0, s0, 0, 0, 0);
        s0 = __builtin_amdgcn_mfma_f32_16x16x32_bf16(qfl[ks], bh0, s0, 0, 0, 0);
        s0 = __builtin_amdgcn_mfma_f32_16x16x32_bf16(qfh[ks], bl0, s0, 0, 0, 0);
        s1 = __builtin_amdgcn_mfma_f32_16x16x32_bf16(qfh[ks], bh1, s1, 0, 0, 0);
        s1 = __builtin_amdgcn_mfma_f32_16x16x32_bf16(qfl[ks], bh1, s1, 0, 0, 0);
        s1 = __builtin_amdgcn_mfma_f32_16x16x32_bf16(qfh[ks], bl1, s1, 0, 0, 0);
      }
#pragma unroll
      for (int j = 0; j < 4; ++j) {
        const int qr = l4 * 4 + j;
        scw[SCIDX(qr, ct * 32 + l15)] = s0[j] * SCALE;
        scw[SCIDX(qr, ct * 32 + 16 + l15)] = s1[j] * SCALE;
      }
    }
    // ---- softmax over 127 cmp scores (in-wave; 4 lanes per query) ----
    {
      const int qq = lane >> 2, qg = lane & 3;
      const int tq = t0 + qq;
      const int nv = (tq >= KSZ - 1) ? ((tq - (KSZ - 1)) / STRD + 1) : 0;
      float x[32];
#pragma unroll
      for (int i = 0; i < 32; ++i) x[i] = scw[SCIDX(qq, qg * 32 + i)];
      float m = NEGF;
#pragma unroll
      for (int i = 0; i < 32; ++i)
        if (qg * 32 + i < nv) m = fmaxf(m, x[i]);
      m = fmaxf(m, __shfl_xor(m, 1));
      m = fmaxf(m, __shfl_xor(m, 2));
      float s = 0.f;
#pragma unroll
      for (int i = 0; i < 32; ++i) {
        x[i] = (qg * 32 + i < nv) ? __expf(x[i] - m) : 0.f;
        s += x[i];
      }
      s += __shfl_xor(s, 1);
      s += __shfl_xor(s, 2);
      const float inv = (nv > 0) ? (1.0f / s) : 0.f;
#pragma unroll
      for (int i = 0; i < 32; ++i) scw[SCIDX(qq, qg * 32 + i)] = x[i] * inv;
    }
    // ---- selection scores + top-16 (exact tie semantics) ----
    {
      const int qq = lane >> 2, jg = lane & 3;
      const int tq = t0 + qq;
      float vj[8];
#pragma unroll
      for (int i = 0; i < 8; ++i) {
        const int j = jg * 8 + i;
        const int lo = (4 * j - 1 > 0) ? 4 * j - 1 : 0;
        const int hi = (4 * j + 3 < NCMP - 1) ? 4 * j + 3 : NCMP - 1;
        float ps = 0.f;
        for (int c = lo; c <= hi; ++c) ps += scw[SCIDX(qq, c)];
        float val = (j * SSZ <= tq) ? ps : -1.0f;
        if (j == (tq >> 6)) val += 1e6f;
        vj[i] = val;
        ssel[qq * 33 + j] = val;
      }
      float sv[32];
#pragma unroll
      for (int jp = 0; jp < 32; ++jp) sv[jp] = ssel[qq * 33 + jp];
#pragma unroll
      for (int i = 0; i < 8; ++i) {
        const int j = jg * 8 + i;
        const float my = vj[i];
        int rank = 0;
#pragma unroll
        for (int jp = 0; jp < 32; ++jp)
          rank += (sv[jp] > my) || (sv[jp] == my && jp < j);
        if (rank < TOPN && (j * SSZ <= tq)) atomicOr(&maskLds[qq], 1u << j);
      }
    }
#pragma unroll
    for (int j = 0; j < 4; ++j) maskq[j] = maskLds[l4 * 4 + j];
    unionW = maskq[0] | maskq[1] | maskq[2] | maskq[3];
    unionW |= __shfl_xor(unionW, 16);
    unionW |= __shfl_xor(unionW, 32);
  } else {
    // ================= W: gates (fp32 exact) =================
    if (lane < 48) {
      const int qloc = lane / 3, g = lane % 3;
      const float* qr_ = q + ((t0 + qloc) * NH + h) * DIM;
      float acc = bg[g];
#pragma unroll
      for (int d4 = 0; d4 < DIM; d4 += 4) {
        const float4 qv = *(const float4*)(qr_ + d4);
        acc += qv.x * wg[(d4 + 0) * 3 + g] + qv.y * wg[(d4 + 1) * 3 + g] +
               qv.z * wg[(d4 + 2) * 3 + g] + qv.w * wg[(d4 + 3) * 3 + g];
      }
      gatesLds[qloc * 3 + g] = 1.0f / (1.0f + __expf(-acc));
    }
  }

  __syncthreads();   // #1: probs + gates visible to W

  f32x4 accO[8];
#pragma unroll
  for (int n = 0; n < 8; ++n) accO[n] = (f32x4){0, 0, 0, 0};
  float mX[4], lX[4];
#pragma unroll
  for (int j = 0; j < 4; ++j) { mX[j] = NEGF; lX[j] = 0.f; }

  char* paw = pa + w * 1024;
  const int ktmax = (t0 + 15) >> 5;

  if (w == 0) {
    // ================= S: selected branch =================
    for (int kt = 0; kt <= ktmax; ++kt) {
      if (!((unionW >> (kt >> 1)) & 1u)) continue;
      const int kt0 = kt << 5;
      const unsigned short* kbase = kb + (h * S_LEN + kt0) * DIM + l4 * 8;
      f32x4 s0 = {0, 0, 0, 0}, s1 = {0, 0, 0, 0};
#pragma unroll
      for (int ks = 0; ks < 4; ++ks) {
        bf16x8 b0 = *(const bf16x8*)(kbase + l15 * DIM + ks * 32);
        bf16x8 b1 = *(const bf16x8*)(kbase + (16 + l15) * DIM + ks * 32);
        s0 = __builtin_amdgcn_mfma_f32_16x16x32_bf16(qfh[ks], b0, s0, 0, 0, 0);
        s1 = __builtin_amdgcn_mfma_f32_16x16x32_bf16(qfh[ks], b1, s1, 0, 0, 0);
      }
#pragma unroll
      for (int j = 0; j < 4; ++j) {
        const int qr = l4 * 4 + j;
        const int tq = t0 + qr;
        const bool mb = (maskq[j] >> (kt >> 1)) & 1u;
        const float v0 = (mb && kt0 + l15 <= tq) ? s0[j] * SCALE : NEGF;
        const float v1 = (mb && kt0 + 16 + l15 <= tq) ? s1[j] * SCALE : NEGF;
        float rm = fmaxf(v0, v1);
        rm = fmaxf(rm, __shfl_xor(rm, 1));
        rm = fmaxf(rm, __shfl_xor(rm, 2));
        rm = fmaxf(rm, __shfl_xor(rm, 4));
        rm = fmaxf(rm, __shfl_xor(rm, 8));
        if (rm > mX[j]) {
          const float sf = __expf(mX[j] - rm);
          lX[j] *= sf;
#pragma unroll
          for (int n = 0; n < 8; ++n) accO[n][j] *= sf;
          mX[j] = rm;
        }
        const float p0 = (v0 > NEGTH) ? __expf(v0 - mX[j]) : 0.f;
        const float p1 = (v1 > NEGTH) ? __expf(v1 - mX[j]) : 0.f;
        float rs = p0 + p1;
        rs += __shfl_xor(rs, 1);
        rs += __shfl_xor(rs, 2);
        rs += __shfl_xor(rs, 4);
        rs += __shfl_xor(rs, 8);
        lX[j] += rs;
        *(unsigned short*)(paw + qr * 64 + ((l15 * 2) ^ ((qr & 3) << 4))) = f2bf(p0);
        *(unsigned short*)(paw + qr * 64 + (((16 + l15) * 2) ^ ((qr & 3) << 4))) = f2bf(p1);
      }
      bf16x8 ap = *(const bf16x8*)(paw + l15 * 64 + ((l4 * 16) ^ ((l15 & 3) << 4)));
      const unsigned short* vbase = vtg + (h * DIM) * S_LEN + kt0 + l4 * 8;
#pragma unroll
      for (int n = 0; n < 8; ++n) {
        bf16x8 bvv = *(const bf16x8*)(vbase + (n * 16 + l15) * S_LEN);
        accO[n] = __builtin_amdgcn_mfma_f32_16x16x32_bf16(ap, bvv, accO[n], 0, 0, 0);
      }
    }
  } else {
    // ================= W: cmp PV =================
    f32x4 accC[8];
#pragma unroll
    for (int n = 0; n < 8; ++n) accC[n] = (f32x4){0, 0, 0, 0};
    for (int ct = 0; ct < nct; ++ct) {
      float f[8];
#pragma unroll
      for (int i = 0; i < 8; ++i) f[i] = scw[SCIDX(l15, ct * 32 + l4 * 8 + i)];
      bf16x8 ap = pack8(f);
      const unsigned short* cvb = cmpvt + (h * 128) * 128 + ct * 32 + l4 * 8;
#pragma unroll
      for (int n = 0; n < 8; ++n) {
        bf16x8 bvv = *(const bf16x8*)(cvb + (n * 16 + l15) * 128);
        accC[n] = __builtin_amdgcn_mfma_f32_16x16x32_bf16(ap, bvv, accC[n], 0, 0, 0);
      }
    }
    // winOut init = g0 * Ocmp (all prob reads above are done; same-wave ordered)
#pragma unroll
    for (int j = 0; j < 4; ++j) {
      const int qr = l4 * 4 + j;
      const float g0 = gatesLds[qr * 3 + 0];
#pragma unroll
      for (int n = 0; n < 8; ++n) scw[SCIDX(qr, n * 16 + l15)] = g0 * accC[n][j];
    }
    // ================= W: window branch =================
    const int ktlo = (t0 >= WINSZ) ? ((t0 - WINSZ) >> 5) : 0;
    for (int kt = ktlo; kt <= ktmax; ++kt) {
      const int kt0 = kt << 5;
      const unsigned short* kbase = kb + (h * S_LEN + kt0) * DIM + l4 * 8;
      f32x4 s0 = {0, 0, 0, 0}, s1 = {0, 0, 0, 0};
#pragma unroll
      for (int ks = 0; ks < 4; ++ks) {
        bf16x8 b0 = *(const bf16x8*)(kbase + l15 * DIM + ks * 32);
        bf16x8 b1 = *(const bf16x8*)(kbase + (16 + l15) * DIM + ks * 32);
        s0 = __builtin_amdgcn_mfma_f32_16x16x32_bf16(qfh[ks], b0, s0, 0, 0, 0);
        s1 = __builtin_amdgcn_mfma_f32_16x16x32_bf16(qfh[ks], b1, s1, 0, 0, 0);
      }
#pragma unroll
      for (int j = 0; j < 4; ++j) {
        const int qr = l4 * 4 + j;
        const int tq = t0 + qr;
        const int c0 = kt0 + l15, c1 = kt0 + 16 + l15;
        const float v0 = (c0 <= tq && c0 >= tq - WINSZ) ? s0[j] * SCALE : NEGF;
        const float v1 = (c1 <= tq && c1 >= tq - WINSZ) ? s1[j] * SCALE : NEGF;
        float rm = fmaxf(v0, v1);
        rm = fmaxf(rm, __shfl_xor(rm, 1));
        rm = fmaxf(rm, __shfl_xor(rm, 2));
        rm = fmaxf(rm, __shfl_xor(rm, 4));
        rm = fmaxf(rm, __shfl_xor(rm, 8));
        if (rm > mX[j]) {
          const float sf = __expf(mX[j] - rm);
          lX[j] *= sf;
#pragma unroll
          for (int n = 0; n < 8; ++n) accO[n][j] *= sf;
          mX[j] = rm;
        }
        const float p0 = (v0 > NEGTH) ? __expf(v0 - mX[j]) : 0.f;
        const float p1 = (v1 > NEGTH) ? __expf(v1 - mX[j]) : 0.f;
        float rs = p0 + p1;
        rs += __shfl_xor(rs, 1);
        rs += __shfl_xor(rs, 2);
        rs += __shfl_xor(rs, 4);
        rs += __shfl_xor(rs, 8);
        lX[j] += rs;
        *(unsigned short*)(paw + qr * 64 + ((l15 * 2) ^ ((qr & 3) << 4))) = f2bf(p0);
        *(unsigned short*)(paw + qr * 64 + (((16 + l15) * 2) ^ ((qr & 3) << 4))) = f2bf(p1);
      }
      bf16x8 ap = *(const bf16x8*)(paw + l15 * 64 + ((l4 * 16) ^ ((l15 & 3) << 4)));
      const unsigned short* vbase = vtg + (h * DIM) * S_LEN + kt0 + l4 * 8;
#pragma unroll
      for (int n = 0; n < 8; ++n) {
        bf16x8 bvv = *(const bf16x8*)(vbase + (n * 16 + l15) * S_LEN);
        accO[n] = __builtin_amdgcn_mfma_f32_16x16x32_bf16(ap, bvv, accO[n], 0, 0, 0);
      }
    }
    // fold window into winOut
#pragma unroll
    for (int j = 0; j < 4; ++j) {
      const int qr = l4 * 4 + j;
      const float g2 = gatesLds[qr * 3 + 2];
      const float rl = 1.0f / lX[j];
#pragma unroll
      for (int n = 0; n < 8; ++n)
        scw[SCIDX(qr, n * 16 + l15)] += g2 * accO[n][j] * rl;
    }
  }

  __syncthreads();   // #2: winOut ready

  if (w == 0) {
#pragma unroll
    for (int j = 0; j < 4; ++j) {
      const int qr = l4 * 4 + j;
      const int tq = t0 + qr;
      const float g1 = gatesLds[qr * 3 + 1];
      const float rl = 1.0f / lX[j];
#pragma unroll
      for (int n = 0; n < 8; ++n)
        out[(tq * NH + h) * DIM + n * 16 + l15] =
            scw[SCIDX(qr, n * 16 + l15)] + g1 * accO[n][j] * rl;
    }
  }
}

extern "C" void kernel_launch(void* const* d_in, const int* in_sizes, int n_in,
                              void* d_out, int out_size, void* d_ws, size_t ws_size,
                              hipStream_t stream) {
  const float* q  = (const float*)d_in[0];
  const float* k  = (const float*)d_in[1];
  const float* v  = (const float*)d_in[2];
  const float* wg = (const float*)d_in[3];
  const float* bg = (const float*)d_in[4];
  float* out = (float*)d_out;

  unsigned short* vtg   = (unsigned short*)d_ws;            // 8 MB
  unsigned short* kb    = vtg + NH * DIM * S_LEN;           // 8 MB
  unsigned short* cmpkh = kb + NH * S_LEN * DIM;            // 512 KB
  unsigned short* cmpkl = cmpkh + NH * 128 * 128;           // 512 KB
  unsigned short* cmpvt = cmpkl + NH * 128 * 128;           // 512 KB

  nsa_build<<<2048, 256, 0, stream>>>(v, k, vtg, kb);
  nsa_compress<<<NH * 128, 128, 0, stream>>>(k, v, cmpkh, cmpkl, cmpvt);
  nsa_main<<<2048, 128, 0, stream>>>(q, wg, bg, kb, vtg, cmpkh, cmpkl, cmpvt, out);
}